// Round 6
// baseline (950.797 us; speedup 1.0000x reference)
//
#include <hip/hip_runtime.h>
#include <math.h>

// Markowitz min-variance via FISTA, one block (512 thr, 8 waves) per problem.
// Q register-resident: thread (r4=tid&63, e=tid>>6) owns Q[4*r4..+3][32*e..+31].
// R8 (on R7; serial phase is LATENCY-bound on one DPP chain — R7 proved
// parallel chains are free):
//  - dual-candidate first trip: s+cnt at BOTH tau_ws and extrapolated tau
//    (4 interleaved DPP chains ~= 1 chain latency); exact-Newton loop after,
//    with cnt per trip (free ILP) so no extra post-loop cnt wsum.
//  - beta off critical path: lane 64 (wave1, idle post-partial) runs the
//    data-independent t-recurrence, publishes beta_{k+1} to a parity-buffered
//    LDS slot during iter k (barrier-ordered). Wave0 just loads it.
//  - partials pre-scaled by -step2 (scale slot in LDS): wave0's reduce + y
//    directly yields v (no serial step2 FMAs).
//  - kept: const bracket [-2,2], Newton tol 1e-4, frozen-w exit 1e-7,
//    publish-y-first, wave0-serial structure (R4/R6 detours documented).

#define NA    256
#define CAPW  0.05f

typedef float v2f __attribute__((ext_vector_type(2)));

// ---- DPP wave-64 reductions ----
template<int CTRL, int RM>
__device__ __forceinline__ float dpp0(float x) {      // old = 0, bound_ctrl = true
    return __int_as_float(__builtin_amdgcn_update_dpp(
        0, __float_as_int(x), CTRL, RM, 0xf, true));
}
template<int CTRL, int RM>
__device__ __forceinline__ float dppI(float x, float ident) { // old = ident
    return __int_as_float(__builtin_amdgcn_update_dpp(
        __float_as_int(ident), __float_as_int(x), CTRL, RM, 0xf, false));
}
__device__ __forceinline__ float bcast63(float x) {
    return __int_as_float(__builtin_amdgcn_readlane(__float_as_int(x), 63));
}
__device__ __forceinline__ float wsum(float x) {
    x += dpp0<0x111, 0xf>(x);   // row_shr:1
    x += dpp0<0x112, 0xf>(x);   // row_shr:2
    x += dpp0<0x114, 0xf>(x);   // row_shr:4
    x += dpp0<0x118, 0xf>(x);   // row_shr:8
    x += dpp0<0x142, 0xa>(x);   // row_bcast:15 -> rows 1,3
    x += dpp0<0x143, 0xc>(x);   // row_bcast:31 -> rows 2,3
    return bcast63(x);
}
__device__ __forceinline__ float wmax(float x) {
    const float I = -1e30f;
    x = fmaxf(x, dppI<0x111, 0xf>(x, I));
    x = fmaxf(x, dppI<0x112, 0xf>(x, I));
    x = fmaxf(x, dppI<0x114, 0xf>(x, I));
    x = fmaxf(x, dppI<0x118, 0xf>(x, I));
    x = fmaxf(x, dppI<0x142, 0xa>(x, I));
    x = fmaxf(x, dppI<0x143, 0xc>(x, I));
    return bcast63(x);
}

__global__ void __launch_bounds__(512, 2)
markowitz_fista(const float* __restrict__ A, float* __restrict__ out)
{
    // 32KB pool: phase 1 = A staging. Afterwards:
    //   [0..2047]    p_lds: 8 partial vectors (pre-scaled by the scale slot)
    //   [2048..2303] y_lds: published y
    //   [2304]       scale slot (1.0 during power phase, -step2 during FISTA)
    //   [2305..2306] beta slots (parity double-buffered, written by lane 64)
    __shared__ float lds_pool[32 * 256];
    __shared__ int   done_flag;

    float* A_lds = lds_pool;
    float* p_lds = lds_pool;
    float* y_lds = lds_pool + 2048;

    const int tid = threadIdx.x;
    const int b   = blockIdx.x;
    const int r4  = tid & 63;
    const int e   = tid >> 6;           // wave id == col-chunk
    const int R0  = r4 * 4;
    const int C0  = e * 32;

    const float* __restrict__ Ab = A + (size_t)b * NA * NA;

    // ---------------- Phase 1: Q = A^T A into registers (packed fp32) -------
    v2f q2[4][16];
    #pragma unroll
    for (int a = 0; a < 4; ++a)
        #pragma unroll
        for (int k = 0; k < 16; ++k) q2[a][k] = (v2f){0.0f, 0.0f};

    for (int it = 0; it < 8; ++it) {
        __syncthreads();
        const float4* src = (const float4*)(Ab + it * 32 * 256);
        float4* dst = (float4*)A_lds;
        #pragma unroll
        for (int qd = 0; qd < 4; ++qd) dst[qd * 512 + tid] = src[qd * 512 + tid];
        __syncthreads();
        for (int ii = 0; ii < 32; ++ii) {
            const float* row = A_lds + ii * 256;
            float4 rv = *(const float4*)(row + R0);
            v2f r0 = {rv.x, rv.x}, r1 = {rv.y, rv.y}, r2 = {rv.z, rv.z}, r3 = {rv.w, rv.w};
            #pragma unroll
            for (int cc = 0; cc < 8; ++cc) {
                float4 cv = *(const float4*)(row + C0 + 4 * cc);
                v2f clo = {cv.x, cv.y}, chi = {cv.z, cv.w};
                q2[0][2*cc  ] = __builtin_elementwise_fma(r0, clo, q2[0][2*cc  ]);
                q2[0][2*cc+1] = __builtin_elementwise_fma(r0, chi, q2[0][2*cc+1]);
                q2[1][2*cc  ] = __builtin_elementwise_fma(r1, clo, q2[1][2*cc  ]);
                q2[1][2*cc+1] = __builtin_elementwise_fma(r1, chi, q2[1][2*cc+1]);
                q2[2][2*cc  ] = __builtin_elementwise_fma(r2, clo, q2[2][2*cc  ]);
                q2[2][2*cc+1] = __builtin_elementwise_fma(r2, chi, q2[2][2*cc+1]);
                q2[3][2*cc  ] = __builtin_elementwise_fma(r3, clo, q2[3][2*cc  ]);
                q2[3][2*cc+1] = __builtin_elementwise_fma(r3, chi, q2[3][2*cc+1]);
            }
        }
    }
    __syncthreads();   // alias safety: all A_lds reads done before p/y reuse

    // all waves: partials of Q*y_lds into p_lds, scaled by lds[2304].
    // Returns true on early-exit (flag read hidden behind the matvec FMAs).
    auto partials = [&](bool chk) -> bool {
        __syncthreads();                               // B1: y_lds / flag / slots visible
        int fl = chk ? done_flag : 0;
        float scl = lds_pool[2304];
        v2f aL0 = {0,0}, aL1 = {0,0}, aL2 = {0,0}, aL3 = {0,0};
        v2f aH0 = {0,0}, aH1 = {0,0}, aH2 = {0,0}, aH3 = {0,0};
        const float* yv = y_lds + C0;
        #pragma unroll
        for (int cc = 0; cc < 8; ++cc) {
            float4 y4 = *(const float4*)(yv + 4 * cc);
            v2f ylo = {y4.x, y4.y}, yhi = {y4.z, y4.w};
            aL0 = __builtin_elementwise_fma(q2[0][2*cc  ], ylo, aL0);
            aH0 = __builtin_elementwise_fma(q2[0][2*cc+1], yhi, aH0);
            aL1 = __builtin_elementwise_fma(q2[1][2*cc  ], ylo, aL1);
            aH1 = __builtin_elementwise_fma(q2[1][2*cc+1], yhi, aH1);
            aL2 = __builtin_elementwise_fma(q2[2][2*cc  ], ylo, aL2);
            aH2 = __builtin_elementwise_fma(q2[2][2*cc+1], yhi, aH2);
            aL3 = __builtin_elementwise_fma(q2[3][2*cc  ], ylo, aL3);
            aH3 = __builtin_elementwise_fma(q2[3][2*cc+1], yhi, aH3);
        }
        if (fl) return true;                           // block-uniform
        v2f s0 = aL0 + aH0, s1 = aL1 + aH1, s2 = aL2 + aH2, s3 = aL3 + aH3;
        *(float4*)(p_lds + e * 256 + R0) =
            make_float4(scl * (s0.x + s0.y), scl * (s1.x + s1.y),
                        scl * (s2.x + s2.y), scl * (s3.x + s3.y));
        __syncthreads();                               // B2: p_lds visible
        return false;
    };
    // wave0: raw reduce of 8 partials (power phase, scale slot = 1.0)
    auto reduceg = [&]() -> float4 {
        float4 r = *(const float4*)(p_lds + 4 * tid);
        #pragma unroll
        for (int ee = 1; ee < 8; ++ee) {
            float4 pv = *(const float4*)(p_lds + ee * 256 + 4 * tid);
            r.x += pv.x; r.y += pv.y; r.z += pv.z; r.w += pv.w;
        }
        return r;
    };

    // ---------------- Phase 2: power iteration for step size ----------------
    // Normalization-free: u_{k+1} = 0.25 * Q u_k (exact pow2 scaling).
    if (tid < 64) {
        *(float4*)(y_lds + 4 * tid) = make_float4(0.0625f, 0.0625f, 0.0625f, 0.0625f);
    }
    if (tid == 0) lds_pool[2304] = 1.0f;   // scale = 1 for power phase
    float u0 = 0.0625f, u1 = 0.0625f, u2 = 0.0625f, u3 = 0.0625f;
    for (int p = 0; p < 30; ++p) {
        partials(false);
        if (tid < 64) {
            float4 g4 = reduceg();
            u0 = 0.25f * g4.x; u1 = 0.25f * g4.y;
            u2 = 0.25f * g4.z; u3 = 0.25f * g4.w;
            *(float4*)(y_lds + 4 * tid) = make_float4(u0, u1, u2, u3);
        }
    }
    partials(false);   // Q*u for Rayleigh quotient

    float tau_ws = 0.0f, tau_pv = 0.0f, rm = 0.0f;
    float wa = 0.f, wb = 0.f, wc = 0.f, wd = 0.f;
    float ya = 0.f, yb = 0.f, yc = 0.f, yd = 0.f;
    if (tid < 64) {
        float4 g4 = reduceg();
        // Rayleigh on unnormalized u: (u.g)/(u.u) — two interleaved wsum chains
        float num = wsum(u0*g4.x + u1*g4.y + u2*g4.z + u3*g4.w);
        float den = wsum(u0*u0 + u1*u1 + u2*u2 + u3*u3);
        float lm = num / (den + 1e-30f);
        float step = 1.0f / (2.0f * lm + 1e-12f);
        wa = wb = wc = wd = 1.0f / 256.0f;    // project(uniform) = uniform (tau=0)
        ya = yb = yc = yd = 1.0f / 256.0f;
        *(float4*)(y_lds + 4 * tid) = make_float4(ya, yb, yc, yd);
        if (tid == 0) {
            lds_pool[2304] = -2.0f * step;    // FISTA partial scale = -step2
            done_flag = 0;
        }
    }
    // beta pipeline state (lane 64 uses it; cheap uniform init everywhere)
    // t_0 = 1; beta_k = (t_k - 1)/t_{k+1}. Maintain tb1 = t_{k+1}, tb2 = t_{k+2}.
    float tb1 = 0.5f * (1.0f + sqrtf(5.0f));                    // t_1
    float tb2 = 0.5f * (1.0f + sqrtf(1.0f + 4.0f * tb1 * tb1)); // t_2
    if (tid == 64) lds_pool[2305] = 0.0f;     // beta_0 (slot 0); ordered by next B1

    // ---------------- Phase 3: FISTA ----------------
    for (int itn = 0; itn < 300; ++itn) {
        if (partials(true)) break;             // frozen-w early exit (uniform)
        if (tid < 64) {
            float bf = lds_pool[2305 + (itn & 1)];   // beta_k (lane-64 pipeline)
            // v = y - step2*g : partials pre-scaled, fold y into the reduce
            float4 r = *(const float4*)(p_lds + 4 * tid);
            #pragma unroll
            for (int ee = 1; ee < 8; ++ee) {
                float4 pv = *(const float4*)(p_lds + ee * 256 + 4 * tid);
                r.x += pv.x; r.y += pv.y; r.z += pv.z; r.w += pv.w;
            }
            float v0 = ya + r.x, v1 = yb + r.y, v2 = yc + r.z, v3 = yd + r.w;

            float lo = -2.0f, hi = 2.0f;
            float tA = fminf(fmaxf(tau_ws, lo), hi);
            float tB = fminf(fmaxf(tau_ws + (tau_ws - tau_pv), lo), hi);

            // dual eval: s,cnt at BOTH candidates — 4 independent DPP chains
            float zA0 = v0 - tA, zA1 = v1 - tA, zA2 = v2 - tA, zA3 = v3 - tA;
            float zB0 = v0 - tB, zB1 = v1 - tB, zB2 = v2 - tB, zB3 = v3 - tB;
            float cA0 = fminf(fmaxf(zA0, -CAPW), CAPW);
            float cA1 = fminf(fmaxf(zA1, -CAPW), CAPW);
            float cA2 = fminf(fmaxf(zA2, -CAPW), CAPW);
            float cA3 = fminf(fmaxf(zA3, -CAPW), CAPW);
            float cB0 = fminf(fmaxf(zB0, -CAPW), CAPW);
            float cB1 = fminf(fmaxf(zB1, -CAPW), CAPW);
            float cB2 = fminf(fmaxf(zB2, -CAPW), CAPW);
            float cB3 = fminf(fmaxf(zB3, -CAPW), CAPW);
            float sA = wsum((cA0 + cA1) + (cA2 + cA3));
            float nA = wsum((fabsf(zA0) < CAPW ? 1.f : 0.f) +
                            (fabsf(zA1) < CAPW ? 1.f : 0.f) +
                            (fabsf(zA2) < CAPW ? 1.f : 0.f) +
                            (fabsf(zA3) < CAPW ? 1.f : 0.f));
            float sB = wsum((cB0 + cB1) + (cB2 + cB3));
            float nB = wsum((fabsf(zB0) < CAPW ? 1.f : 0.f) +
                            (fabsf(zB1) < CAPW ? 1.f : 0.f) +
                            (fabsf(zB2) < CAPW ? 1.f : 0.f) +
                            (fabsf(zB3) < CAPW ? 1.f : 0.f));
            float dA = sA - 1.0f, dB = sB - 1.0f;

            float tau, cnt, sm1;
            if (fabsf(dA) <= 1e-4f)      { tau = tA; sm1 = dA; cnt = nA; }
            else if (fabsf(dB) <= 1e-4f) { tau = tB; sm1 = dB; cnt = nB; }
            else {
                if (dA > 0.0f) lo = fmaxf(lo, tA); else hi = fminf(hi, tA);
                if (dB > 0.0f) lo = fmaxf(lo, tB); else hi = fminf(hi, tB);
                float tP, dP, nP;
                if (fabsf(dA) <= fabsf(dB)) { tP = tA; dP = dA; nP = nA; }
                else                        { tP = tB; dP = dB; nP = nB; }
                tau = tP + dP / fmaxf(nP, 1.0f);     // exact-Newton (s' = -n_int)
                if (!(tau > lo && tau < hi)) tau = 0.5f * (lo + hi);
                bool have = false;
                cnt = 1.0f; sm1 = 0.0f;
                for (int ni = 0; ni < 8; ++ni) {
                    float z0 = v0 - tau, z1 = v1 - tau, z2 = v2 - tau, z3 = v3 - tau;
                    float c0 = fminf(fmaxf(z0, -CAPW), CAPW);
                    float c1 = fminf(fmaxf(z1, -CAPW), CAPW);
                    float c2 = fminf(fmaxf(z2, -CAPW), CAPW);
                    float c3 = fminf(fmaxf(z3, -CAPW), CAPW);
                    float s = wsum((c0 + c1) + (c2 + c3));
                    cnt = wsum((fabsf(z0) < CAPW ? 1.f : 0.f) +
                               (fabsf(z1) < CAPW ? 1.f : 0.f) +
                               (fabsf(z2) < CAPW ? 1.f : 0.f) +
                               (fabsf(z3) < CAPW ? 1.f : 0.f));
                    sm1 = s - 1.0f;
                    if (fabsf(sm1) <= 1e-4f) { have = true; break; }
                    if (sm1 > 0.0f) lo = tau; else hi = tau;
                    float tn2 = tau + sm1 / fmaxf(cnt, 1.0f);
                    if (!(tn2 > lo && tn2 < hi)) tn2 = 0.5f * (lo + hi);
                    tau = tn2;
                }
                if (!have) {   // bound-exit: re-eval at final tau
                    float z0 = v0 - tau, z1 = v1 - tau, z2 = v2 - tau, z3 = v3 - tau;
                    float c0 = fminf(fmaxf(z0, -CAPW), CAPW);
                    float c1 = fminf(fmaxf(z1, -CAPW), CAPW);
                    float c2 = fminf(fmaxf(z2, -CAPW), CAPW);
                    float c3 = fminf(fmaxf(z3, -CAPW), CAPW);
                    float s = wsum((c0 + c1) + (c2 + c3));
                    cnt = wsum((fabsf(z0) < CAPW ? 1.f : 0.f) +
                               (fabsf(z1) < CAPW ? 1.f : 0.f) +
                               (fabsf(z2) < CAPW ? 1.f : 0.f) +
                               (fabsf(z3) < CAPW ? 1.f : 0.f));
                    sm1 = s - 1.0f;
                }
            }
            // exact active-set tau == one Newton step at the converged point
            tau = tau + sm1 / fmaxf(cnt, 1.0f);
            tau_pv = tau_ws;
            tau_ws = tau;
            float w0n = fminf(fmaxf(v0 - tau, -CAPW), CAPW);
            float w1n = fminf(fmaxf(v1 - tau, -CAPW), CAPW);
            float w2n = fminf(fmaxf(v2 - tau, -CAPW), CAPW);
            float w3n = fminf(fmaxf(v3 - tau, -CAPW), CAPW);

            float y0n = w0n + bf * (w0n - wa);
            float y1n = w1n + bf * (w1n - wb);
            float y2n = w2n + bf * (w2n - wc);
            float y3n = w3n + bf * (w3n - wd);

            // publish y FIRST (earlier handoff), then bookkeeping
            *(float4*)(y_lds + 4 * tid) = make_float4(y0n, y1n, y2n, y3n);

            // frozen-w detection (8-iter window)
            float dm = fmaxf(fmaxf(fabsf(w0n - wa), fabsf(w1n - wb)),
                             fmaxf(fabsf(w2n - wc), fabsf(w3n - wd)));
            rm = fmaxf(rm, dm);
            if ((itn & 7) == 7) {
                float rmax = wmax(rm);
                if (rmax < 1e-7f && tid == 0) done_flag = 1;
                rm = 0.0f;
            }

            wa = w0n; wb = w1n; wc = w2n; wd = w3n;
            ya = y0n; yb = y1n; yc = y2n; yd = y3n;
        } else if (tid == 64) {
            // data-independent beta pipeline: write beta_{k+1} for next iter
            float bnew = (tb1 - 1.0f) / tb2;
            lds_pool[2305 + ((itn + 1) & 1)] = bnew;
            tb1 = tb2;
            tb2 = 0.5f * (1.0f + sqrtf(1.0f + 4.0f * tb2 * tb2));
        }
    }

    if (tid < 64) {
        *(float4*)(out + b * 256 + 4 * tid) = make_float4(wa, wb, wc, wd);
    }
}

extern "C" void kernel_launch(void* const* d_in, const int* in_sizes, int n_in,
                              void* d_out, int out_size, void* d_ws, size_t ws_size,
                              hipStream_t stream) {
    (void)in_sizes; (void)n_in; (void)d_ws; (void)ws_size; (void)out_size;
    const float* A = (const float*)d_in[0];
    float* out = (float*)d_out;
    hipLaunchKernelGGL(markowitz_fista, dim3(512), dim3(512), 0, stream, A, out);
}